// Round 1
// baseline (482.537 us; speedup 1.0000x reference)
//
#include <hip/hip_runtime.h>
#include <hip/hip_fp16.h>

typedef _Float16 f16;
typedef _Float16 f16x8 __attribute__((ext_vector_type(8)));
typedef _Float16 f16x4 __attribute__((ext_vector_type(4)));
typedef float f32x4 __attribute__((ext_vector_type(4)));

#define AS1 __attribute__((address_space(1)))
#define AS3 __attribute__((address_space(3)))

__device__ __forceinline__ void g2l16(const void* g, void* l) {
  __builtin_amdgcn_global_load_lds((const AS1 void*)g, (AS3 void*)l, 16, 0, 0);
}

// ---------------- build X = [x_r | x_i] as fp16, [16384, 512] ----------------
__global__ __launch_bounds__(256) void build_x(const float* __restrict__ qr,
                                               const float* __restrict__ qi,
                                               f16* __restrict__ X) {
  long i = (long)blockIdx.x * 256 + threadIdx.x;  // one float4 per thread
  long e = i * 4;
  int m = (int)(e >> 9);
  int k = (int)(e & 511);
  const float* src = (k < 256) ? (qr + (long)m * 256 + k)
                               : (qi + (long)m * 256 + (k - 256));
  float4 v = *(const float4*)src;
  f16x4 h = {(f16)v.x, (f16)v.y, (f16)v.z, (f16)v.w};
  *(f16x4*)(X + e) = h;
}

// ------- build Wbig [1536, 512] fp16, rows n = [qr,qi,kr,ki,vr,vi] blocks -----
// real out: [Wr | -Wi], imag out: [Wi | Wr]  (y = x @ W.T semantics)
__global__ __launch_bounds__(256) void build_w(const float* __restrict__ wqr,
                                               const float* __restrict__ wqi,
                                               const float* __restrict__ wkr,
                                               const float* __restrict__ wki,
                                               const float* __restrict__ wvr,
                                               const float* __restrict__ wvi,
                                               f16* __restrict__ W) {
  long i = (long)blockIdx.x * 256 + threadIdx.x;
  long e = i * 4;
  int n = (int)(e >> 9);
  int k = (int)(e & 511);
  int sel = n >> 8;       // 0..5
  int row = n & 255;
  int k2 = k & 255;
  bool hi = (k >= 256);
  const float *Wr, *Wi;
  if ((sel >> 1) == 0)      { Wr = wqr; Wi = wqi; }
  else if ((sel >> 1) == 1) { Wr = wkr; Wi = wki; }
  else                      { Wr = wvr; Wi = wvi; }
  const float* src;
  float sgn = 1.0f;
  if ((sel & 1) == 0) {  // real output
    if (!hi) src = Wr + (long)row * 256 + k2;
    else   { src = Wi + (long)row * 256 + k2; sgn = -1.0f; }
  } else {               // imag output
    if (!hi) src = Wi + (long)row * 256 + k2;
    else     src = Wr + (long)row * 256 + k2;
  }
  float4 v = *(const float4*)src;
  f16x4 h = {(f16)(sgn * v.x), (f16)(sgn * v.y), (f16)(sgn * v.z), (f16)(sgn * v.w)};
  *(f16x4*)(W + e) = h;
}

// ---------------- generic NT GEMM, fp16 A/B, 128x128 tile, BK=64 ----------------
// MODE 0: C = fp16, ldc fixed 1536 (projection output P)
// MODE 1: C = fp32 * scale, ldc 4096, batched by cstr (raw scores)
template <int MODE>
__global__ __launch_bounds__(256) void gemm_nt(const f16* __restrict__ A, int lda, long astr,
                                               const f16* __restrict__ B, int ldb, long bstr,
                                               int K, float scale,
                                               void* __restrict__ C0, long cstr) {
  __shared__ __align__(16) f16 As[128 * 64];
  __shared__ __align__(16) f16 Bs[128 * 64];
  const int z = blockIdx.z;
  const f16* Ab = A + (long)z * astr;
  const f16* Bb = B + (long)z * bstr;
  const int tid = threadIdx.x;
  const int wave = tid >> 6, lane = tid & 63;
  const int bm = blockIdx.y * 128, bn = blockIdx.x * 128;
  const int wm = (wave >> 1) * 64, wn = (wave & 1) * 64;
  const int lr = lane & 15, lg = lane >> 4;

  const int srow = wave * 8 + (lane >> 3);   // staging row within tile
  const int sk = (lane & 7) * 8;             // staging k offset (8 f16 = 16B)

  f32x4 acc[4][4] = {};

  for (int kt = 0; kt < K; kt += 64) {
#pragma unroll
    for (int it = 0; it < 4; ++it) {
      int r = srow + it * 32;
      g2l16(Ab + (long)(bm + r) * lda + kt + sk, (char*)As + it * 4096 + wave * 1024);
      g2l16(Bb + (long)(bn + r) * ldb + kt + sk, (char*)Bs + it * 4096 + wave * 1024);
    }
    __syncthreads();
#pragma unroll
    for (int kk = 0; kk < 2; ++kk) {
      f16x8 af[4], bf[4];
#pragma unroll
      for (int f = 0; f < 4; ++f) {
        af[f] = *(const f16x8*)(As + (wm + f * 16 + lr) * 64 + kk * 32 + lg * 8);
        bf[f] = *(const f16x8*)(Bs + (wn + f * 16 + lr) * 64 + kk * 32 + lg * 8);
      }
#pragma unroll
      for (int fm = 0; fm < 4; ++fm)
#pragma unroll
        for (int fn = 0; fn < 4; ++fn)
          acc[fm][fn] = __builtin_amdgcn_mfma_f32_16x16x32_f16(af[fm], bf[fn], acc[fm][fn], 0, 0, 0);
    }
    __syncthreads();
  }

#pragma unroll
  for (int fm = 0; fm < 4; ++fm) {
#pragma unroll
    for (int fn = 0; fn < 4; ++fn) {
#pragma unroll
      for (int r = 0; r < 4; ++r) {
        int row = bm + wm + fm * 16 + lg * 4 + r;
        int col = bn + wn + fn * 16 + lr;
        float v = acc[fm][fn][r];
        if (MODE == 0) {
          ((f16*)C0)[(long)row * 1536 + col] = (f16)v;
        } else {
          ((float*)C0)[(long)z * cstr + (long)row * 4096 + col] = v * scale;
        }
      }
    }
  }
}

// ------------- transpose V block of P into VT [4][512][4096] fp16 -------------
__global__ __launch_bounds__(256) void build_vt(const f16* __restrict__ P,
                                                f16* __restrict__ VT) {
  __shared__ f16 t[64][66];  // 66: stride 33 dwords -> conflict-free transpose read
  const int tid = threadIdx.x;
  const long b = blockIdx.z;
  const f16* src = P + (b * 4096 + (long)blockIdx.x * 64) * 1536 + 1024 + blockIdx.y * 64;
#pragma unroll
  for (int it = 0; it < 16; ++it) {
    int lin = it * 256 + tid;
    int i = lin >> 6, j = lin & 63;  // i = k-row, j = n-col
    t[i][j] = src[(long)i * 1536 + j];
  }
  __syncthreads();
  f16* dst = VT + (b * 512 + (long)blockIdx.y * 64) * 4096 + blockIdx.x * 64;
#pragma unroll
  for (int it = 0; it < 16; ++it) {
    int lin = it * 256 + tid;
    int i = lin >> 6, j = lin & 63;  // i = n-row, j = k-col
    dst[(long)i * 4096 + j] = t[j][i];
  }
}

// ---------------- row softmax over attn [16384 rows x 4096], in-place ----------------
__global__ __launch_bounds__(256) void softmax_rows(float* __restrict__ attn) {
  float* p = attn + (long)blockIdx.x * 4096;
  const int tid = threadIdx.x;
  float4 v[4];
  float m = -1e30f;
#pragma unroll
  for (int j = 0; j < 4; ++j) {
    v[j] = *(const float4*)&p[(j * 256 + tid) * 4];
    m = fmaxf(m, fmaxf(fmaxf(v[j].x, v[j].y), fmaxf(v[j].z, v[j].w)));
  }
#pragma unroll
  for (int off = 32; off >= 1; off >>= 1) m = fmaxf(m, __shfl_xor(m, off));
  __shared__ float sm[8];
  if ((tid & 63) == 0) sm[tid >> 6] = m;
  __syncthreads();
  m = fmaxf(fmaxf(sm[0], sm[1]), fmaxf(sm[2], sm[3]));
  float s = 0.0f;
#pragma unroll
  for (int j = 0; j < 4; ++j) {
    v[j].x = __expf(v[j].x - m);
    v[j].y = __expf(v[j].y - m);
    v[j].z = __expf(v[j].z - m);
    v[j].w = __expf(v[j].w - m);
    s += v[j].x + v[j].y + v[j].z + v[j].w;
  }
#pragma unroll
  for (int off = 32; off >= 1; off >>= 1) s += __shfl_xor(s, off);
  if ((tid & 63) == 0) sm[4 + (tid >> 6)] = s;
  __syncthreads();
  s = sm[4] + sm[5] + sm[6] + sm[7];
  float inv = 1.0f / s;
#pragma unroll
  for (int j = 0; j < 4; ++j) {
    v[j].x *= inv; v[j].y *= inv; v[j].z *= inv; v[j].w *= inv;
    *(float4*)&p[(j * 256 + tid) * 4] = v[j];
  }
}

// ------------- PV GEMM: out = attn(fp32, converted) @ VT^T, N=512 -------------
__global__ __launch_bounds__(256) void gemm_pv(const float* __restrict__ A,  // attn
                                               const f16* __restrict__ Bv,   // VT
                                               float* __restrict__ outR,
                                               float* __restrict__ outI) {
  __shared__ __align__(16) f16 As[128 * 64];
  __shared__ __align__(16) f16 Bs[128 * 64];
  const int z = blockIdx.z;
  const float* Ab = A + (long)z * 4096 * 4096;
  const f16* Bb = Bv + (long)z * 512 * 4096;
  const int tid = threadIdx.x;
  const int wave = tid >> 6, lane = tid & 63;
  const int bm = blockIdx.y * 128, bn = blockIdx.x * 128;
  const int wm = (wave >> 1) * 64, wn = (wave & 1) * 64;
  const int lr = lane & 15, lg = lane >> 4;

  const int brow = wave * 8 + (lane >> 3);
  const int bk = (lane & 7) * 8;
  const int arow0 = tid >> 4;      // 0..15
  const int ak = (tid & 15) * 4;   // 0..60

  f32x4 acc[4][4] = {};

  for (int kt = 0; kt < 4096; kt += 64) {
#pragma unroll
    for (int it = 0; it < 4; ++it) {
      int r = brow + it * 32;
      g2l16(Bb + (long)(bn + r) * 4096 + kt + bk, (char*)Bs + it * 4096 + wave * 1024);
    }
#pragma unroll
    for (int it = 0; it < 8; ++it) {
      int r = arow0 + it * 16;
      float4 v = *(const float4*)&Ab[(long)(bm + r) * 4096 + kt + ak];
      f16x4 h = {(f16)v.x, (f16)v.y, (f16)v.z, (f16)v.w};
      *(f16x4*)(As + r * 64 + ak) = h;
    }
    __syncthreads();
#pragma unroll
    for (int kk = 0; kk < 2; ++kk) {
      f16x8 af[4], bf[4];
#pragma unroll
      for (int f = 0; f < 4; ++f) {
        af[f] = *(const f16x8*)(As + (wm + f * 16 + lr) * 64 + kk * 32 + lg * 8);
        bf[f] = *(const f16x8*)(Bs + (wn + f * 16 + lr) * 64 + kk * 32 + lg * 8);
      }
#pragma unroll
      for (int fm = 0; fm < 4; ++fm)
#pragma unroll
        for (int fn = 0; fn < 4; ++fn)
          acc[fm][fn] = __builtin_amdgcn_mfma_f32_16x16x32_f16(af[fm], bf[fn], acc[fm][fn], 0, 0, 0);
    }
    __syncthreads();
  }

#pragma unroll
  for (int fm = 0; fm < 4; ++fm) {
#pragma unroll
    for (int fn = 0; fn < 4; ++fn) {
#pragma unroll
      for (int r = 0; r < 4; ++r) {
        int row = bm + wm + fm * 16 + lg * 4 + r;
        int col = bn + wn + fn * 16 + lr;
        float v = acc[fm][fn][r];
        long o = ((long)z * 4096 + row) * 256 + (col & 255);
        if (col < 256) outR[o] = v; else outI[o] = v;
      }
    }
  }
}

extern "C" void kernel_launch(void* const* d_in, const int* in_sizes, int n_in,
                              void* d_out, int out_size, void* d_ws, size_t ws_size,
                              hipStream_t stream) {
  const float* qr  = (const float*)d_in[0];
  const float* qi  = (const float*)d_in[1];
  const float* wqr = (const float*)d_in[2];
  const float* wqi = (const float*)d_in[3];
  const float* wkr = (const float*)d_in[4];
  const float* wki = (const float*)d_in[5];
  const float* wvr = (const float*)d_in[6];
  const float* wvi = (const float*)d_in[7];

  float* outR = (float*)d_out;                       // [4,4096,256]
  float* outI = outR + (size_t)4 * 4096 * 256;       // [4,4096,256]
  float* attn = outI + (size_t)4 * 4096 * 256;       // [4,4096,4096]

  char* ws = (char*)d_ws;
  f16* X  = (f16*)ws;                                              // [16384,512]   16 MB
  f16* W  = (f16*)(ws + (size_t)16384 * 512 * 2);                  // [1536,512]    1.5 MB
  f16* P  = (f16*)(ws + (size_t)16384 * 512 * 2 + (size_t)1536 * 512 * 2);  // [16384,1536] 48 MB
  f16* VT = (f16*)(ws + (size_t)16384 * 512 * 2 + (size_t)1536 * 512 * 2 +
                   (size_t)16384 * 1536 * 2);                      // [4,512,4096]  16 MB

  build_x<<<8192, 256, 0, stream>>>(qr, qi, X);
  build_w<<<768, 256, 0, stream>>>(wqr, wqi, wkr, wki, wvr, wvi, W);

  // P = X @ Wbig^T : M=16384, N=1536, K=512
  gemm_nt<0><<<dim3(12, 128, 1), 256, 0, stream>>>(X, 512, 0L, W, 512, 0L, 512, 1.0f,
                                                   (void*)P, 0L);

  build_vt<<<dim3(64, 8, 4), 256, 0, stream>>>(P, VT);

  // scores = q_flat @ k_flat^T * scale : per batch M=N=4096, K=512
  gemm_nt<1><<<dim3(32, 32, 4), 256, 0, stream>>>(P, 1536, (long)4096 * 1536,
                                                  P + 512, 1536, (long)4096 * 1536,
                                                  512, 0.0625f,
                                                  (void*)attn, (long)4096 * 4096);

  softmax_rows<<<16384, 256, 0, stream>>>(attn);

  // out = attn @ [v_r | v_i] : per batch M=4096, N=512, K=4096
  gemm_pv<<<dim3(4, 32, 4), 256, 0, stream>>>(attn, VT, outR, outI);
}

// Round 2
// 395.859 us; speedup vs baseline: 1.2190x; 1.2190x over previous
//
#include <hip/hip_runtime.h>
#include <hip/hip_fp16.h>

typedef _Float16 f16;
typedef _Float16 f16x8 __attribute__((ext_vector_type(8)));
typedef _Float16 f16x4 __attribute__((ext_vector_type(4)));
typedef float f32x4 __attribute__((ext_vector_type(4)));

#define AS1 __attribute__((address_space(1)))
#define AS3 __attribute__((address_space(3)))

__device__ __forceinline__ void g2l16(const void* g, void* l) {
  __builtin_amdgcn_global_load_lds((const AS1 void*)g, (AS3 void*)l, 16, 0, 0);
}

// bijective XCD-chunk swizzle (requires nwg % 8 == 0; true for all our grids)
__device__ __forceinline__ void xcd_swz(int& bx, int& by, int& bz) {
  int gx = gridDim.x, gy = gridDim.y;
  int nwg = gx * gy * gridDim.z;
  int lin = (blockIdx.z * gy + blockIdx.y) * gx + blockIdx.x;
  int swz = (lin & 7) * (nwg >> 3) + (lin >> 3);
  bx = swz % gx;
  int t = swz / gx;
  by = t % gy;
  bz = t / gy;
}

// ---------------- build X = [x_r | x_i] as fp16, [16384, 512] ----------------
__global__ __launch_bounds__(256) void build_x(const float* __restrict__ qr,
                                               const float* __restrict__ qi,
                                               f16* __restrict__ X) {
  long i = (long)blockIdx.x * 256 + threadIdx.x;  // one float4 per thread
  long e = i * 4;
  int m = (int)(e >> 9);
  int k = (int)(e & 511);
  const float* src = (k < 256) ? (qr + (long)m * 256 + k)
                               : (qi + (long)m * 256 + (k - 256));
  float4 v = *(const float4*)src;
  f16x4 h = {(f16)v.x, (f16)v.y, (f16)v.z, (f16)v.w};
  *(f16x4*)(X + e) = h;
}

// ------- build Wbig [1536, 512] fp16, rows n = [qr,qi,kr,ki,vr,vi] blocks -----
// real out: [Wr | -Wi], imag out: [Wi | Wr]  (y = x @ W.T semantics)
__global__ __launch_bounds__(256) void build_w(const float* __restrict__ wqr,
                                               const float* __restrict__ wqi,
                                               const float* __restrict__ wkr,
                                               const float* __restrict__ wki,
                                               const float* __restrict__ wvr,
                                               const float* __restrict__ wvi,
                                               f16* __restrict__ W) {
  long i = (long)blockIdx.x * 256 + threadIdx.x;
  long e = i * 4;
  int n = (int)(e >> 9);
  int k = (int)(e & 511);
  int sel = n >> 8;       // 0..5
  int row = n & 255;
  int k2 = k & 255;
  bool hi = (k >= 256);
  const float *Wr, *Wi;
  if ((sel >> 1) == 0)      { Wr = wqr; Wi = wqi; }
  else if ((sel >> 1) == 1) { Wr = wkr; Wi = wki; }
  else                      { Wr = wvr; Wi = wvi; }
  const float* src;
  float sgn = 1.0f;
  if ((sel & 1) == 0) {  // real output
    if (!hi) src = Wr + (long)row * 256 + k2;
    else   { src = Wi + (long)row * 256 + k2; sgn = -1.0f; }
  } else {               // imag output
    if (!hi) src = Wi + (long)row * 256 + k2;
    else     src = Wr + (long)row * 256 + k2;
  }
  float4 v = *(const float4*)src;
  f16x4 h = {(f16)(sgn * v.x), (f16)(sgn * v.y), (f16)(sgn * v.z), (f16)(sgn * v.w)};
  *(f16x4*)(W + e) = h;
}

// ---------------- generic NT GEMM, fp16 A/B, 128x128 tile, BK=64 ----------------
// LDS layout: [row][64 f16] with 16B-slot XOR swizzle: stored[r][c] = logical[r][c ^ (r&7)]
// Staged via global_load_lds (linear dest) + pre-swizzled per-lane SOURCE address.
// MODE 0: C = fp16, ldc fixed 1536 (projection output P)
// MODE 1: C = fp32 * scale, ldc 4096, batched by cstr (raw scores)
template <int MODE>
__global__ __launch_bounds__(256) void gemm_nt(const f16* __restrict__ A, int lda, long astr,
                                               const f16* __restrict__ B, int ldb, long bstr,
                                               int K, float scale,
                                               void* __restrict__ C0, long cstr) {
  __shared__ __align__(16) f16 As[128 * 64];
  __shared__ __align__(16) f16 Bs[128 * 64];
  int bx, by, bz;
  xcd_swz(bx, by, bz);
  const f16* Ab = A + (long)bz * astr;
  const f16* Bb = B + (long)bz * bstr;
  const int tid = threadIdx.x;
  const int wave = tid >> 6, lane = tid & 63;
  const int bm = by * 128, bn = bx * 128;
  const int wm = (wave >> 1) * 64, wn = (wave & 1) * 64;
  const int lr = lane & 15, lg = lane >> 4;

  const int srow = wave * 8 + (lane >> 3);            // staging row within tile
  const int sk = ((lane & 7) ^ (lane >> 3)) * 8;      // pre-swizzled k offset (row&7 == lane>>3)

  f32x4 acc[4][4] = {};

  for (int kt = 0; kt < K; kt += 64) {
#pragma unroll
    for (int it = 0; it < 4; ++it) {
      int r = srow + it * 32;
      g2l16(Ab + (long)(bm + r) * lda + kt + sk, (char*)As + it * 4096 + wave * 1024);
      g2l16(Bb + (long)(bn + r) * ldb + kt + sk, (char*)Bs + it * 4096 + wave * 1024);
    }
    __syncthreads();
#pragma unroll
    for (int kk = 0; kk < 2; ++kk) {
      f16x8 af[4], bf[4];
#pragma unroll
      for (int f = 0; f < 4; ++f) {
        int slot = kk * 4 + lg;
        int sw = (slot ^ (lr & 7)) * 8;
        af[f] = *(const f16x8*)(As + (wm + f * 16 + lr) * 64 + sw);
        bf[f] = *(const f16x8*)(Bs + (wn + f * 16 + lr) * 64 + sw);
      }
#pragma unroll
      for (int fm = 0; fm < 4; ++fm)
#pragma unroll
        for (int fn = 0; fn < 4; ++fn)
          acc[fm][fn] = __builtin_amdgcn_mfma_f32_16x16x32_f16(af[fm], bf[fn], acc[fm][fn], 0, 0, 0);
    }
    __syncthreads();
  }

#pragma unroll
  for (int fm = 0; fm < 4; ++fm) {
#pragma unroll
    for (int fn = 0; fn < 4; ++fn) {
#pragma unroll
      for (int r = 0; r < 4; ++r) {
        int row = bm + wm + fm * 16 + lg * 4 + r;
        int col = bn + wn + fn * 16 + lr;
        float v = acc[fm][fn][r];
        if (MODE == 0) {
          ((f16*)C0)[(long)row * 1536 + col] = (f16)v;
        } else {
          ((float*)C0)[(long)bz * cstr + (long)row * 4096 + col] = v * scale;
        }
      }
    }
  }
}

// ------------- transpose V block of P into VT [4][512][4096] fp16 -------------
__global__ __launch_bounds__(256) void build_vt(const f16* __restrict__ P,
                                                f16* __restrict__ VT) {
  __shared__ f16 t[64][66];
  const int tid = threadIdx.x;
  const long b = blockIdx.z;
  const f16* src = P + (b * 4096 + (long)blockIdx.x * 64) * 1536 + 1024 + blockIdx.y * 64;
#pragma unroll
  for (int it = 0; it < 16; ++it) {
    int lin = it * 256 + tid;
    int i = lin >> 6, j = lin & 63;
    t[i][j] = src[(long)i * 1536 + j];
  }
  __syncthreads();
  f16* dst = VT + (b * 512 + (long)blockIdx.y * 64) * 4096 + blockIdx.x * 64;
#pragma unroll
  for (int it = 0; it < 16; ++it) {
    int lin = it * 256 + tid;
    int i = lin >> 6, j = lin & 63;
    dst[(long)i * 4096 + j] = t[j][i];
  }
}

// ---------------- row softmax over attn [16384 rows x 4096], in-place ----------------
__global__ __launch_bounds__(256) void softmax_rows(float* __restrict__ attn) {
  float* p = attn + (long)blockIdx.x * 4096;
  const int tid = threadIdx.x;
  float4 v[4];
  float m = -1e30f;
#pragma unroll
  for (int j = 0; j < 4; ++j) {
    v[j] = *(const float4*)&p[(j * 256 + tid) * 4];
    m = fmaxf(m, fmaxf(fmaxf(v[j].x, v[j].y), fmaxf(v[j].z, v[j].w)));
  }
#pragma unroll
  for (int off = 32; off >= 1; off >>= 1) m = fmaxf(m, __shfl_xor(m, off));
  __shared__ float sm[8];
  if ((tid & 63) == 0) sm[tid >> 6] = m;
  __syncthreads();
  m = fmaxf(fmaxf(sm[0], sm[1]), fmaxf(sm[2], sm[3]));
  float s = 0.0f;
#pragma unroll
  for (int j = 0; j < 4; ++j) {
    v[j].x = __expf(v[j].x - m);
    v[j].y = __expf(v[j].y - m);
    v[j].z = __expf(v[j].z - m);
    v[j].w = __expf(v[j].w - m);
    s += v[j].x + v[j].y + v[j].z + v[j].w;
  }
#pragma unroll
  for (int off = 32; off >= 1; off >>= 1) s += __shfl_xor(s, off);
  if ((tid & 63) == 0) sm[4 + (tid >> 6)] = s;
  __syncthreads();
  s = sm[4] + sm[5] + sm[6] + sm[7];
  float inv = 1.0f / s;
#pragma unroll
  for (int j = 0; j < 4; ++j) {
    v[j].x *= inv; v[j].y *= inv; v[j].z *= inv; v[j].w *= inv;
    *(float4*)&p[(j * 256 + tid) * 4] = v[j];
  }
}

// ------------- PV GEMM: out = attn(fp32 -> f16 reg-staged) @ VT^T, N=512 -------------
__global__ __launch_bounds__(256) void gemm_pv(const float* __restrict__ A,  // attn
                                               const f16* __restrict__ Bv,   // VT
                                               float* __restrict__ outR,
                                               float* __restrict__ outI) {
  __shared__ __align__(16) f16 As[128 * 64];
  __shared__ __align__(16) f16 Bs[128 * 64];
  int bx, by, bz;
  xcd_swz(bx, by, bz);
  const float* Ab = A + (long)bz * 4096 * 4096;
  const f16* Bb = Bv + (long)bz * 512 * 4096;
  const int tid = threadIdx.x;
  const int wave = tid >> 6, lane = tid & 63;
  const int bm = by * 128, bn = bx * 128;
  const int wm = (wave >> 1) * 64, wn = (wave & 1) * 64;
  const int lr = lane & 15, lg = lane >> 4;

  const int brow = wave * 8 + (lane >> 3);
  const int bk = ((lane & 7) ^ (lane >> 3)) * 8;      // pre-swizzled source offset
  const int arow0 = tid >> 4;      // 0..15
  const int ak = (tid & 15) * 4;   // 0..60 (f16/float elements)
  const int acol16 = (tid & 15) >> 1;   // 16B slot within row
  const int ahalf = (tid & 1) * 4;      // 8B half (in f16 elems)

  f32x4 acc[4][4] = {};

  for (int kt = 0; kt < 4096; kt += 64) {
#pragma unroll
    for (int it = 0; it < 4; ++it) {
      int r = brow + it * 32;
      g2l16(Bb + (long)(bn + r) * 4096 + kt + bk, (char*)Bs + it * 4096 + wave * 1024);
    }
#pragma unroll
    for (int it = 0; it < 8; ++it) {
      int r = arow0 + it * 16;
      float4 v = *(const float4*)&Ab[(long)(bm + r) * 4096 + kt + ak];
      f16x4 h = {(f16)v.x, (f16)v.y, (f16)v.z, (f16)v.w};
      *(f16x4*)(As + r * 64 + (acol16 ^ (r & 7)) * 8 + ahalf) = h;   // swizzled ds_write
    }
    __syncthreads();
#pragma unroll
    for (int kk = 0; kk < 2; ++kk) {
      f16x8 af[4], bf[4];
#pragma unroll
      for (int f = 0; f < 4; ++f) {
        int slot = kk * 4 + lg;
        int sw = (slot ^ (lr & 7)) * 8;
        af[f] = *(const f16x8*)(As + (wm + f * 16 + lr) * 64 + sw);
        bf[f] = *(const f16x8*)(Bs + (wn + f * 16 + lr) * 64 + sw);
      }
#pragma unroll
      for (int fm = 0; fm < 4; ++fm)
#pragma unroll
        for (int fn = 0; fn < 4; ++fn)
          acc[fm][fn] = __builtin_amdgcn_mfma_f32_16x16x32_f16(af[fm], bf[fn], acc[fm][fn], 0, 0, 0);
    }
    __syncthreads();
  }

#pragma unroll
  for (int fm = 0; fm < 4; ++fm) {
#pragma unroll
    for (int fn = 0; fn < 4; ++fn) {
#pragma unroll
      for (int r = 0; r < 4; ++r) {
        int row = bm + wm + fm * 16 + lg * 4 + r;
        int col = bn + wn + fn * 16 + lr;
        float v = acc[fm][fn][r];
        long o = ((long)bz * 4096 + row) * 256 + (col & 255);
        if (col < 256) outR[o] = v; else outI[o] = v;
      }
    }
  }
}

extern "C" void kernel_launch(void* const* d_in, const int* in_sizes, int n_in,
                              void* d_out, int out_size, void* d_ws, size_t ws_size,
                              hipStream_t stream) {
  const float* qr  = (const float*)d_in[0];
  const float* qi  = (const float*)d_in[1];
  const float* wqr = (const float*)d_in[2];
  const float* wqi = (const float*)d_in[3];
  const float* wkr = (const float*)d_in[4];
  const float* wki = (const float*)d_in[5];
  const float* wvr = (const float*)d_in[6];
  const float* wvi = (const float*)d_in[7];

  float* outR = (float*)d_out;                       // [4,4096,256]
  float* outI = outR + (size_t)4 * 4096 * 256;       // [4,4096,256]
  float* attn = outI + (size_t)4 * 4096 * 256;       // [4,4096,4096]

  char* ws = (char*)d_ws;
  f16* X  = (f16*)ws;                                              // [16384,512]   16 MB
  f16* W  = (f16*)(ws + (size_t)16384 * 512 * 2);                  // [1536,512]    1.5 MB
  f16* P  = (f16*)(ws + (size_t)16384 * 512 * 2 + (size_t)1536 * 512 * 2);  // [16384,1536] 48 MB
  f16* VT = (f16*)(ws + (size_t)16384 * 512 * 2 + (size_t)1536 * 512 * 2 +
                   (size_t)16384 * 1536 * 2);                      // [4,512,4096]  16 MB

  build_x<<<8192, 256, 0, stream>>>(qr, qi, X);
  build_w<<<768, 256, 0, stream>>>(wqr, wqi, wkr, wki, wvr, wvi, W);

  // P = X @ Wbig^T : M=16384, N=1536, K=512  (nwg=1536, %8==0)
  gemm_nt<0><<<dim3(12, 128, 1), 256, 0, stream>>>(X, 512, 0L, W, 512, 0L, 512, 1.0f,
                                                   (void*)P, 0L);

  build_vt<<<dim3(64, 8, 4), 256, 0, stream>>>(P, VT);

  // scores = q_flat @ k_flat^T * scale : per batch M=N=4096, K=512  (nwg=4096)
  gemm_nt<1><<<dim3(32, 32, 4), 256, 0, stream>>>(P, 1536, (long)4096 * 1536,
                                                  P + 512, 1536, (long)4096 * 1536,
                                                  512, 0.0625f,
                                                  (void*)attn, (long)4096 * 4096);

  softmax_rows<<<16384, 256, 0, stream>>>(attn);

  // out = attn @ [v_r | v_i] : per batch M=4096, N=512, K=4096  (nwg=512)
  gemm_pv<<<dim3(4, 32, 4), 256, 0, stream>>>(attn, VT, outR, outI);
}